// Round 7
// baseline (522.697 us; speedup 1.0000x reference)
//
#include <hip/hip_runtime.h>
#include <math.h>

#define B_ 16
#define C_ 129
#define T_ 2000
#define NF_ 40
#define ED_ 64
#define K_ 16
#define TP_ 500

// workspace float offsets
#define OFF_SB2 1040     // 40     folded sconv bias
#define OFF_PWC 1088     // 3200   pw weights * pbn scale
#define OFF_PB2 4288     // 80     folded pw bias
#define OFF_WP  4368     // 1280   wx0 @ proj_w  (16x80)
#define OFF_BP  5648     // 16     wx0 @ proj_b + b0
#define OFF_M0  5664     // 256    L0@L0.T - exp(ll0) I
#define OFF_M1  5920     // 256    L1@L1.T - exp(ll1) I
#define OFF_W1A 6224     // 768    tconv A-frag prepack (3 mt x 64 lanes x 8 bf16)
#define OFF_W2U 8192     // bf16 A-frag prepack of sconv weights: 396288 ushort
#define OFF_XP  1495040  // 16*500*16  per-step cell0 input projection
#define OFF_S2R 1623040  // 1.28M  sconv output (single-owner stores, no atomics)

typedef __attribute__((ext_vector_type(8))) short s8v;
typedef __attribute__((ext_vector_type(4))) float f4v;

#define XROW 292         // xs row stride: 256 t + 24 halo + 12 left pad

__device__ __forceinline__ float elu_f(float x) {
    return x > 0.f ? x : (__expf(x) - 1.f);
}
// tanh(x) given a2 = 2*log2(e)*x: 1 - 2*rcp(exp2(a2)+1); saturates at +-inf.
__device__ __forceinline__ float tanh2e_f(float a2) {
    return fmaf(-2.f,
                __builtin_amdgcn_rcpf(__builtin_amdgcn_exp2f(a2) + 1.f), 1.f);
}
// round-half-up fp32 -> bf16
__device__ __forceinline__ unsigned bfr(float v) {
    return (__float_as_uint(v) + 0x8000u) >> 16;
}

// DPP helpers: row_ror:n ctrl = 0x120+n, rows of 16 lanes.
#define DPPF(v, ctrl) __int_as_float(__builtin_amdgcn_update_dpp( \
    0, __float_as_int(v), (ctrl), 0xF, 0xF, false))

#define RSUM16(s) do {                     \
    s += DPPF(s, 0x128);                   \
    s += DPPF(s, 0x124);                   \
    s += DPPF(s, 0x122);                   \
    s += DPPF(s, 0x121);                   \
} while (0)

// wave-uniform broadcast of lane L's value (SGPR result)
#define RDLANE(v, L) __int_as_float(__builtin_amdgcn_readlane(__float_as_int(v), (L)))

#define C2F 2.8853900817779268f   // 2*log2(e)

struct P0 {
    const float *tconv_w, *tconv_b, *tbn_g, *tbn_b, *tbn_m, *tbn_v;
    const float *sconv_b, *sbn_g, *sbn_b, *sbn_m, *sbn_v;
    const float *pw_w, *pw_b, *pbn_g, *pbn_b, *pbn_m, *pbn_v;
    const float *proj_w, *proj_b, *wx0, *b0, *L0, *ll0, *L1, *ll1;
    const float *sconv_w;
    float* ws;
};

// Merged setup (zeroing pass REMOVED — k1 is now single-owner store):
// blocks [0,194) repack sconv bf16 A-frags; [194,202) run the table setup.
__global__ __launch_bounds__(256) void k0_all(P0 p) {
    const int tid = threadIdx.x;
    float* ws = p.ws;
    const float eps = 1e-5f;

    if (blockIdx.x < 194) {
        const int e = blockIdx.x * 256 + tid;
        if (e >= C_ * 3 * 2 * 64) return;
        unsigned short* w2b = (unsigned short*)(ws + OFF_W2U);
        const int c = e / 384;
        int r = e - c * 384;
        const int mt = r >> 7; r &= 127;
        const int kc = r >> 6;
        const int lane = r & 63;
        const int g = mt * 16 + (lane & 15);
        const float sinv = (g < NF_) ? p.sbn_g[g] * rsqrtf(p.sbn_v[g] + 1e-5f) : 0.f;
        unsigned short o[8];
#pragma unroll
        for (int j = 0; j < 8; ++j) {
            const int f = kc * 32 + (lane >> 4) * 8 + j;
            float v = 0.f;
            if (g < NF_ && f < NF_) v = p.sconv_w[g * (NF_ * C_) + f * C_ + c] * sinv;
            o[j] = (unsigned short)bfr(v);
        }
        unsigned short* dst = w2b + (size_t)e * 8;
#pragma unroll
        for (int j = 0; j < 8; ++j) dst[j] = o[j];
        return;
    }

    const int gtid = (blockIdx.x - 194) * 256 + tid;
    const int stride = 8 * 256;
    // tconv A-frag prepack (bf16): A[m=f][k=tap], K=32; tap 25 = folded bias
    for (int e = gtid; e < 192; e += stride) {
        const int mt = e >> 6, L = e & 63;
        const int f = mt * 16 + (L & 15);
        float inv = 0.f, bias = 0.f;
        if (f < NF_) {
            inv = p.tbn_g[f] / sqrtf(p.tbn_v[f] + eps);
            bias = p.tconv_b[f] * inv + p.tbn_b[f] - p.tbn_m[f] * inv;
        }
        unsigned short* dst = ((unsigned short*)(ws + OFF_W1A)) + e * 8;
#pragma unroll
        for (int j = 0; j < 8; ++j) {
            const int k = (L >> 4) * 8 + j;
            float v = 0.f;
            if (f < NF_) {
                if (k < 25) v = p.tconv_w[f * 25 + k] * inv;
                else if (k == 25) v = bias;
            }
            dst[j] = (unsigned short)bfr(v);
        }
    }
    for (int f = gtid; f < NF_; f += stride) {
        const float sinv = p.sbn_g[f] / sqrtf(p.sbn_v[f] + eps);
        ws[OFF_SB2 + f] = p.sconv_b[f] * sinv + p.sbn_b[f] - p.sbn_m[f] * sinv;
    }
    for (int e = gtid; e < 3200; e += stride) {
        const int g = e / 40;
        const float pinv = p.pbn_g[g] / sqrtf(p.pbn_v[g] + eps);
        ws[OFF_PWC + e] = p.pw_w[e] * pinv;
    }
    for (int g = gtid; g < 80; g += stride) {
        const float pinv = p.pbn_g[g] / sqrtf(p.pbn_v[g] + eps);
        ws[OFF_PB2 + g] = p.pw_b[g] * pinv + p.pbn_b[g] - p.pbn_m[g] * pinv;
    }
    for (int e = gtid; e < 1280; e += stride) {
        const int k = e / 80, g = e - k * 80;
        float a = 0.f;
        for (int ee = 0; ee < ED_; ++ee)
            a = fmaf(p.wx0[k * ED_ + ee], p.proj_w[ee * 80 + g], a);
        ws[OFF_WP + e] = a;
    }
    for (int k = gtid; k < K_; k += stride) {
        float a = p.b0[k];
        for (int ee = 0; ee < ED_; ++ee)
            a = fmaf(p.wx0[k * ED_ + ee], p.proj_b[ee], a);
        ws[OFF_BP + k] = a;
    }
    for (int e = gtid; e < 256; e += stride) {
        const int k = e >> 4, j = e & 15;
        float a0 = 0.f, a1 = 0.f;
        for (int i = 0; i < 16; ++i) {
            a0 = fmaf(p.L0[k * 16 + i], p.L0[j * 16 + i], a0);
            a1 = fmaf(p.L1[k * 16 + i], p.L1[j * 16 + i], a1);
        }
        if (k == j) { a0 -= expf(p.ll0[0]); a1 -= expf(p.ll1[0]); }
        ws[OFF_M0 + e] = a0;
        ws[OFF_M1 + e] = a1;
    }
}

// Both convs on MFMA. Round-6 change: ATOMIC-FREE single-owner blocks.
// grid = 128 (16 b x 8 t-tiles); each block loops ALL 129 channels in 8
// staged chunks (same verified inner loop; acc regs accumulate across
// chunks), epilogue is a plain store. Eliminates 12.6M cross-XCD
// atomicAdds and the k0 zeroing pass.
__global__ __launch_bounds__(256, 4) void k1_mfma(
    const float* __restrict__ x, const unsigned short* __restrict__ w1a,
    const unsigned short* __restrict__ w2b, float* __restrict__ s2raw) {
    __shared__ float xs[17 * XROW];
    __shared__ unsigned int vsI[2048];      // 4 waves x 8 rows x 64 words

    const int tid = threadIdx.x;
    const int tile = blockIdx.x & 7;
    const int b = blockIdx.x >> 3;
    const int t0 = tile << 8;
    const int w = tid >> 6;
    const int lane = tid & 63;
    const int n = lane & 15;
    const int q = lane >> 4;
    const int qh = q >> 1;
    const int q1_2 = (q & 1) * 2;
    const bool q3 = (q == 3);
    const int wb = w << 9;
    const int w64 = w << 6;
    const int ln8 = n + q * 8;

    // rows 6,7 of each wave's vsI panel are read (channels 40-63 pad) but
    // never written -> zero-init once; writes only touch rows 0-5.
    for (int i = tid; i < 2048; i += 256) vsI[i] = 0u;

    const s8v* w1a8 = (const s8v*)w1a;
    s8v wA[3];
#pragma unroll
    for (int mt = 0; mt < 3; ++mt) wA[mt] = w1a8[mt * 64 + lane];

    f4v acc[4][3];
#pragma unroll
    for (int nt = 0; nt < 4; ++nt)
#pragma unroll
        for (int mt = 0; mt < 3; ++mt) acc[nt][mt] = (f4v)0.f;

    const s8v* w2b8 = (const s8v*)w2b;
    const f4v z4 = (f4v)0.f;

    for (int chunk = 0; chunk < 8; ++chunk) {
        const int c0 = (chunk * C_) >> 3;
        const int c1 = ((chunk + 1) * C_) >> 3;
        const int cc = c1 - c0;

        __syncthreads();   // previous chunk's readers done before restage
        for (int e = tid; e < cc * XROW; e += 256) {
            const int cl = e / XROW;
            const int i = e - cl * XROW;
            const int t = t0 - 12 + i;
            float v = 0.f;
            if ((unsigned)t < (unsigned)T_) v = x[(b * C_ + c0 + cl) * T_ + t];
            xs[e] = v;
        }
        __syncthreads();

        for (int cl = 0; cl < cc; ++cl) {
            const int c = c0 + cl;
            s8v af[3][2];
#pragma unroll
            for (int mt = 0; mt < 3; ++mt)
#pragma unroll
                for (int kc = 0; kc < 2; ++kc)
                    af[mt][kc] = w2b8[((c * 3 + mt) * 2 + kc) * 64 + lane];

            const float* xrow = &xs[cl * XROW + w64 + ln8];

#pragma unroll
            for (int nt = 0; nt < 4; ++nt) {
                float bx[8];
#pragma unroll
                for (int j = 0; j < 8; ++j) bx[j] = xrow[nt * 16 + j];
                if (q3) bx[1] = 1.0f;
                unsigned pw_[4];
#pragma unroll
                for (int jj = 0; jj < 4; ++jj)
                    pw_[jj] = bfr(bx[2 * jj]) |
                        ((__float_as_uint(bx[2 * jj + 1]) + 0x8000u) & 0xFFFF0000u);
                const s8v bh = *(const s8v*)pw_;
#pragma unroll
                for (int mt = 0; mt < 3; ++mt) {
                    const f4v vT = __builtin_amdgcn_mfma_f32_16x16x32_bf16(
                        wA[mt], bh, z4, 0, 0, 0);
                    const float e0 = elu_f(vT[0]);
                    const float e1 = elu_f(vT[1]);
                    const float e2 = elu_f(vT[2]);
                    const float e3 = elu_f(vT[3]);
                    const unsigned lo = bfr(e0) |
                        ((__float_as_uint(e1) + 0x8000u) & 0xFFFF0000u);
                    const unsigned hi = bfr(e2) |
                        ((__float_as_uint(e3) + 0x8000u) & 0xFFFF0000u);
                    const int base = wb + ((2 * mt + qh) << 6) + (n << 2) + q1_2;
                    vsI[base] = lo;
                    vsI[base + 1] = hi;
                }
                __builtin_amdgcn_wave_barrier();
                const s8v b0 = *(const s8v*)&vsI[wb + (q << 6) + (n << 2)];
                const s8v b1 = *(const s8v*)&vsI[wb + ((4 + q) << 6) + (n << 2)];
#pragma unroll
                for (int mt = 0; mt < 3; ++mt) {
                    acc[nt][mt] = __builtin_amdgcn_mfma_f32_16x16x32_bf16(
                        af[mt][0], b0, acc[nt][mt], 0, 0, 0);
                    acc[nt][mt] = __builtin_amdgcn_mfma_f32_16x16x32_bf16(
                        af[mt][1], b1, acc[nt][mt], 0, 0, 0);
                }
                __builtin_amdgcn_wave_barrier();
            }
        }
    }

    // single-owner epilogue: plain stores (no atomics, no zero-init needed)
#pragma unroll
    for (int nt = 0; nt < 4; ++nt) {
        const int t = t0 + w * 64 + nt * 16 + n;
        if (t >= T_) continue;
#pragma unroll
        for (int mt = 0; mt < 3; ++mt) {
#pragma unroll
            for (int r = 0; r < 4; ++r) {
                const int g = mt * 16 + q * 4 + r;
                if (g < NF_)
                    s2raw[(b * NF_ + g) * T_ + t] = acc[nt][mt][r];
            }
        }
    }
}

// Fused dw/pw/pool/proj (round-0 verified, unchanged).
__global__ __launch_bounds__(256) void k2_dwpw(
    const float* __restrict__ s2raw, const float* __restrict__ sb2,
    const float* __restrict__ dw_w, const float* __restrict__ dw_b,
    const float* __restrict__ pwc, const float* __restrict__ pb2,
    const float* __restrict__ WP, const float* __restrict__ bp,
    float* __restrict__ xp) {
    __shared__ float st[NF_ * 114];
    __shared__ float dwo[NF_ * 100];
    __shared__ float dwwl[NF_ * 15];
    __shared__ float dwbl[NF_];
    __shared__ float pwcl[80 * 40];
    __shared__ float pb2l[80];
    __shared__ float WPl[K_ * 80];
    __shared__ float bpl[K_];
    __shared__ float po[80 * 25];
    const int tid = threadIdx.x;
    const int b = blockIdx.x / 20;
    const int tp0 = (blockIdx.x % 20) * 25;
    const int tbase = tp0 * 4 - 7;
    for (int e = tid; e < NF_ * 114; e += 256) {
        const int f = e / 114;
        const int i = e - f * 114;
        const int t = tbase + i;
        float v = 0.f;
        if ((unsigned)t < (unsigned)T_)
            v = elu_f(s2raw[(b * NF_ + f) * T_ + t] + sb2[f]);
        st[e] = v;
    }
    for (int e = tid; e < 600; e += 256) dwwl[e] = dw_w[e];
    for (int e = tid; e < 3200; e += 256) pwcl[e] = pwc[e];
    for (int e = tid; e < 1280; e += 256) WPl[e] = WP[e];
    if (tid < NF_) dwbl[tid] = dw_b[tid];
    if (tid < 80) pb2l[tid] = pb2[tid];
    if (tid < K_) bpl[tid] = bp[tid];
    __syncthreads();
    for (int e = tid; e < 4000; e += 256) {
        const int f = e / 100;
        const int tq = e - f * 100;
        float a = dwbl[f];
#pragma unroll
        for (int kk = 0; kk < 15; ++kk)
            a = fmaf(dwwl[f * 15 + kk], st[f * 114 + tq + kk], a);
        dwo[e] = a;
    }
    __syncthreads();
    for (int e = tid; e < 2000; e += 256) {
        const int g = e / 25;
        const int tp = e - g * 25;
        float sum = 0.f;
#pragma unroll
        for (int dt = 0; dt < 4; ++dt) {
            float a = pb2l[g];
            for (int f = 0; f < NF_; ++f)
                a = fmaf(pwcl[g * 40 + f], dwo[f * 100 + tp * 4 + dt], a);
            sum += elu_f(a);
        }
        po[e] = sum * 0.25f;
    }
    __syncthreads();
    for (int e = tid; e < 400; e += 256) {
        const int tp = e >> 4;
        const int k = e & 15;
        float a = bpl[k];
        for (int g = 0; g < 80; ++g)
            a = fmaf(WPl[k * 80 + g], po[g * 25 + tp], a);
        xp[(b * TP_ + tp0 + tp) * K_ + k] = a;
    }
}

// Scan via readlane broadcast (verified local optimum — frozen).
#define SCAN_STEP(I, S) do {                                              \
    float sH0[16], sH1[16];                                               \
    _Pragma("unroll")                                                     \
    for (int j = 0; j < 16; ++j) {                                        \
        sH0[j] = RDLANE(vA, 32 + j);                                      \
        sH1[j] = RDLANE(vA, j);                                           \
    }                                                                     \
    float a0 = 0.f, a1 = 0.f, a2 = 0.f, a3 = 0.f;                         \
    float c0 = 0.f, c1 = 0.f, c2 = 0.f, c3 = 0.f;                         \
    _Pragma("unroll")                                                     \
    for (int j = 0; j < 16; j += 4) {                                     \
        a0 = fmaf(WA[j],     sH0[j],     a0);                             \
        a1 = fmaf(WA[j + 1], sH0[j + 1], a1);                             \
        a2 = fmaf(WA[j + 2], sH0[j + 2], a2);                             \
        a3 = fmaf(WA[j + 3], sH0[j + 3], a3);                             \
        c0 = fmaf(WB[j],     sH1[j],     c0);                             \
        c1 = fmaf(WB[j + 1], sH1[j + 1], c1);                             \
        c2 = fmaf(WB[j + 2], sH1[j + 2], c2);                             \
        c3 = fmaf(WB[j + 3], sH1[j + 3], c3);                             \
    }                                                                     \
    const float xv = xn[S];                                               \
    int tf = (I) + 5; if (tf > TP_ - 1) tf = TP_ - 1;                     \
    xn[S] = xpb[tf * K_];                                                 \
    const float cadd = lower ? b1r : xv;                                  \
    const float pre = (((a0 + a1) + (a2 + a3)) +                          \
                       ((c0 + c1) + (c2 + c3))) + cadd;                   \
    float s1 = pre, s2 = pre * pre;                                       \
    RSUM16(s1);                                                           \
    RSUM16(s2);                                                           \
    const float mu = s1 * 0.0625f;                                        \
    const float var = fmaf(s2, 0.0625f, -mu * mu);                        \
    vA = tanh2e_f(fmaf((pre - mu) * rsqrtf(var + 1e-5f), gg, bb));        \
} while (0)

__global__ __launch_bounds__(64, 1) void k3_scan(
    const float* __restrict__ xp, const float* __restrict__ M0,
    const float* __restrict__ M1, const float* __restrict__ wx1,
    const float* __restrict__ b1, const float* __restrict__ ln0_g,
    const float* __restrict__ ln0_b, const float* __restrict__ ln1_g,
    const float* __restrict__ ln1_b, float* __restrict__ out) {
    const int lane = threadIdx.x;
    const int k = lane & 15;
    const bool lower = lane < 32;
    const int b = blockIdx.x;

    float WA[16], WB[16];
#pragma unroll
    for (int j = 0; j < 16; ++j) {
        const float m0 = M0[k * 16 + j];
        const float m1 = M1[k * 16 + j];
        const float wx = wx1[k * 16 + j];
        WA[j] = lower ? wx : m0;   // coefficient on h0
        WB[j] = lower ? m1 : 0.f;  // coefficient on h1
    }
    const float b1r = b1[k];
    const float g0 = C2F * ln0_g[k], be0 = C2F * ln0_b[k];
    const float gg = lower ? C2F * ln1_g[k] : g0;
    const float bb = lower ? C2F * ln1_b[k] : be0;
    const float* xpb = xp + b * TP_ * K_ + k;

    // prologue: h0_0 = tanh(LN(x_0)) computed by all lanes
    float h0_0;
    {
        const float x0 = xpb[0];
        float s1 = x0, s2 = x0 * x0;
        RSUM16(s1);
        RSUM16(s2);
        const float mu = s1 * 0.0625f;
        const float var = fmaf(s2, 0.0625f, -mu * mu);
        h0_0 = tanh2e_f(fmaf((x0 - mu) * rsqrtf(var + 1e-5f), g0, be0));
    }
    // vA: upper = h0 state (h0_0), lower = h1 state (h1_{-1} = 0)
    float vA = lower ? 0.f : h0_0;

    float xn[4];
    xn[0] = xpb[1 * K_];
    xn[1] = xpb[2 * K_];
    xn[2] = xpb[3 * K_];
    xn[3] = xpb[4 * K_];

    // iter i (0..499): upper -> h0_{i+1}; lower -> h1_i (uses h0_i, h1_{i-1})
    for (int i = 0; i < TP_; i += 4) {
        SCAN_STEP(i + 0, 0);
        SCAN_STEP(i + 1, 1);
        SCAN_STEP(i + 2, 2);
        SCAN_STEP(i + 3, 3);
    }
    if (lane < 16) {
        out[b * K_ + k] = vA;               // Z = h1_{499} (row 0 state)
        if (k == 0) out[256 + b] = 1.0f;    // alpha = softmax over size-1 axis
    }
}

extern "C" void kernel_launch(void* const* d_in, const int* in_sizes, int n_in,
                              void* d_out, int out_size, void* d_ws, size_t ws_size,
                              hipStream_t stream) {
    const float* x       = (const float*)d_in[0];
    const float* dw_w    = (const float*)d_in[13];
    const float* dw_b    = (const float*)d_in[14];
    const float* wx1     = (const float*)d_in[29];
    const float* b1      = (const float*)d_in[32];
    const float* ln0_g   = (const float*)d_in[27];
    const float* ln0_b   = (const float*)d_in[28];
    const float* ln1_g   = (const float*)d_in[33];
    const float* ln1_b   = (const float*)d_in[34];
    float* ws = (float*)d_ws;
    float* out = (float*)d_out;

    P0 p;
    p.tconv_w = (const float*)d_in[1]; p.tconv_b = (const float*)d_in[2];
    p.tbn_g = (const float*)d_in[3]; p.tbn_b = (const float*)d_in[4];
    p.tbn_m = (const float*)d_in[5]; p.tbn_v = (const float*)d_in[6];
    p.sconv_b = (const float*)d_in[8];
    p.sbn_g = (const float*)d_in[9]; p.sbn_b = (const float*)d_in[10];
    p.sbn_m = (const float*)d_in[11]; p.sbn_v = (const float*)d_in[12];
    p.pw_w = (const float*)d_in[15]; p.pw_b = (const float*)d_in[16];
    p.pbn_g = (const float*)d_in[17]; p.pbn_b = (const float*)d_in[18];
    p.pbn_m = (const float*)d_in[19]; p.pbn_v = (const float*)d_in[20];
    p.proj_w = (const float*)d_in[21]; p.proj_b = (const float*)d_in[22];
    p.wx0 = (const float*)d_in[23]; p.b0 = (const float*)d_in[26];
    p.L0 = (const float*)d_in[24]; p.ll0 = (const float*)d_in[25];
    p.L1 = (const float*)d_in[30]; p.ll1 = (const float*)d_in[31];
    p.sconv_w = (const float*)d_in[7];
    p.ws = ws;

    unsigned short* w2b = (unsigned short*)(ws + OFF_W2U);
    unsigned short* w1a = (unsigned short*)(ws + OFF_W1A);

    k0_all<<<dim3(202), dim3(256), 0, stream>>>(p);
    k1_mfma<<<dim3(128), dim3(256), 0, stream>>>(x, w1a, w2b, ws + OFF_S2R);
    k2_dwpw<<<dim3(320), dim3(256), 0, stream>>>(ws + OFF_S2R, ws + OFF_SB2,
                                                 dw_w, dw_b, ws + OFF_PWC,
                                                 ws + OFF_PB2, ws + OFF_WP, ws + OFF_BP,
                                                 ws + OFF_XP);
    k3_scan<<<dim3(16), dim3(64), 0, stream>>>(ws + OFF_XP, ws + OFF_M0, ws + OFF_M1,
                                               wx1, b1, ln0_g, ln0_b, ln1_g, ln1_b, out);
}

// Round 8
// 360.972 us; speedup vs baseline: 1.4480x; 1.4480x over previous
//
#include <hip/hip_runtime.h>
#include <math.h>

#define B_ 16
#define C_ 129
#define T_ 2000
#define NF_ 40
#define ED_ 64
#define K_ 16
#define TP_ 500

// workspace float offsets
#define OFF_SB2 1040     // 40     folded sconv bias
#define OFF_PWC 1088     // 3200   pw weights * pbn scale
#define OFF_PB2 4288     // 80     folded pw bias
#define OFF_WP  4368     // 1280   wx0 @ proj_w  (16x80)
#define OFF_BP  5648     // 16     wx0 @ proj_b + b0
#define OFF_M0  5664     // 256    L0@L0.T - exp(ll0) I
#define OFF_M1  5920     // 256    L1@L1.T - exp(ll1) I
#define OFF_W1A 6224     // 768    tconv A-frag prepack (3 mt x 64 lanes x 8 bf16)
#define OFF_W2U 8192     // bf16 A-frag prepack of sconv weights: 396288 ushort
#define OFF_XP  1495040  // 16*500*16  per-step cell0 input projection
#define OFF_S2R 1623040  // sconv accumulator; slice 0 of up to 8
#define SLICE_  1280000  // B_*NF_*T_ floats per slice
// sliced mode needs OFF_S2R + 8*SLICE_ = 11,863,040 floats (~45.3 MB)

typedef __attribute__((ext_vector_type(8))) short s8v;
typedef __attribute__((ext_vector_type(4))) float f4v;

#define XROW 292         // xs row stride: 256 t + 24 halo + 12 left pad

__device__ __forceinline__ float elu_f(float x) {
    return x > 0.f ? x : (__expf(x) - 1.f);
}
// tanh(x) given a2 = 2*log2(e)*x: 1 - 2*rcp(exp2(a2)+1); saturates at +-inf.
__device__ __forceinline__ float tanh2e_f(float a2) {
    return fmaf(-2.f,
                __builtin_amdgcn_rcpf(__builtin_amdgcn_exp2f(a2) + 1.f), 1.f);
}
// round-half-up fp32 -> bf16
__device__ __forceinline__ unsigned bfr(float v) {
    return (__float_as_uint(v) + 0x8000u) >> 16;
}

// DPP helpers: row_ror:n ctrl = 0x120+n, rows of 16 lanes.
#define DPPF(v, ctrl) __int_as_float(__builtin_amdgcn_update_dpp( \
    0, __float_as_int(v), (ctrl), 0xF, 0xF, false))

#define RSUM16(s) do {                     \
    s += DPPF(s, 0x128);                   \
    s += DPPF(s, 0x124);                   \
    s += DPPF(s, 0x122);                   \
    s += DPPF(s, 0x121);                   \
} while (0)

// wave-uniform broadcast of lane L's value (SGPR result)
#define RDLANE(v, L) __int_as_float(__builtin_amdgcn_readlane(__float_as_int(v), (L)))

#define C2F 2.8853900817779268f   // 2*log2(e)

struct P0 {
    const float *tconv_w, *tconv_b, *tbn_g, *tbn_b, *tbn_m, *tbn_v;
    const float *sconv_b, *sbn_g, *sbn_b, *sbn_m, *sbn_v;
    const float *pw_w, *pw_b, *pbn_g, *pbn_b, *pbn_m, *pbn_v;
    const float *proj_w, *proj_b, *wx0, *b0, *L0, *ll0, *L1, *ll1;
    const float *sconv_w;
    float* ws;
};

// Merged setup: blocks [0,1250) zero s2raw slice 0 (atomic fallback);
// [1250,1444) repack sconv bf16 A-frags; [1444,1452) table setup.
__global__ __launch_bounds__(256) void k0_all(P0 p) {
    const int tid = threadIdx.x;
    float* ws = p.ws;
    const float eps = 1e-5f;

    if (blockIdx.x < 1250) {
        const int i = blockIdx.x * 256 + tid;
        if (i < 320000)
            ((float4*)(ws + OFF_S2R))[i] = make_float4(0.f, 0.f, 0.f, 0.f);
        return;
    }
    if (blockIdx.x < 1444) {
        const int e = (blockIdx.x - 1250) * 256 + tid;
        if (e >= C_ * 3 * 2 * 64) return;
        unsigned short* w2b = (unsigned short*)(ws + OFF_W2U);
        const int c = e / 384;
        int r = e - c * 384;
        const int mt = r >> 7; r &= 127;
        const int kc = r >> 6;
        const int lane = r & 63;
        const int g = mt * 16 + (lane & 15);
        const float sinv = (g < NF_) ? p.sbn_g[g] * rsqrtf(p.sbn_v[g] + 1e-5f) : 0.f;
        unsigned short o[8];
#pragma unroll
        for (int j = 0; j < 8; ++j) {
            const int f = kc * 32 + (lane >> 4) * 8 + j;
            float v = 0.f;
            if (g < NF_ && f < NF_) v = p.sconv_w[g * (NF_ * C_) + f * C_ + c] * sinv;
            o[j] = (unsigned short)bfr(v);
        }
        unsigned short* dst = w2b + (size_t)e * 8;
#pragma unroll
        for (int j = 0; j < 8; ++j) dst[j] = o[j];
        return;
    }

    const int gtid = (blockIdx.x - 1444) * 256 + tid;
    const int stride = 8 * 256;
    // tconv A-frag prepack (bf16): A[m=f][k=tap], K=32; tap 25 = folded bias
    for (int e = gtid; e < 192; e += stride) {
        const int mt = e >> 6, L = e & 63;
        const int f = mt * 16 + (L & 15);
        float inv = 0.f, bias = 0.f;
        if (f < NF_) {
            inv = p.tbn_g[f] / sqrtf(p.tbn_v[f] + eps);
            bias = p.tconv_b[f] * inv + p.tbn_b[f] - p.tbn_m[f] * inv;
        }
        unsigned short* dst = ((unsigned short*)(ws + OFF_W1A)) + e * 8;
#pragma unroll
        for (int j = 0; j < 8; ++j) {
            const int k = (L >> 4) * 8 + j;
            float v = 0.f;
            if (f < NF_) {
                if (k < 25) v = p.tconv_w[f * 25 + k] * inv;
                else if (k == 25) v = bias;
            }
            dst[j] = (unsigned short)bfr(v);
        }
    }
    for (int f = gtid; f < NF_; f += stride) {
        const float sinv = p.sbn_g[f] / sqrtf(p.sbn_v[f] + eps);
        ws[OFF_SB2 + f] = p.sconv_b[f] * sinv + p.sbn_b[f] - p.sbn_m[f] * sinv;
    }
    for (int e = gtid; e < 3200; e += stride) {
        const int g = e / 40;
        const float pinv = p.pbn_g[g] / sqrtf(p.pbn_v[g] + eps);
        ws[OFF_PWC + e] = p.pw_w[e] * pinv;
    }
    for (int g = gtid; g < 80; g += stride) {
        const float pinv = p.pbn_g[g] / sqrtf(p.pbn_v[g] + eps);
        ws[OFF_PB2 + g] = p.pw_b[g] * pinv + p.pbn_b[g] - p.pbn_m[g] * pinv;
    }
    for (int e = gtid; e < 1280; e += stride) {
        const int k = e / 80, g = e - k * 80;
        float a = 0.f;
        for (int ee = 0; ee < ED_; ++ee)
            a = fmaf(p.wx0[k * ED_ + ee], p.proj_w[ee * 80 + g], a);
        ws[OFF_WP + e] = a;
    }
    for (int k = gtid; k < K_; k += stride) {
        float a = p.b0[k];
        for (int ee = 0; ee < ED_; ++ee)
            a = fmaf(p.wx0[k * ED_ + ee], p.proj_b[ee], a);
        ws[OFF_BP + k] = a;
    }
    for (int e = gtid; e < 256; e += stride) {
        const int k = e >> 4, j = e & 15;
        float a0 = 0.f, a1 = 0.f;
        for (int i = 0; i < 16; ++i) {
            a0 = fmaf(p.L0[k * 16 + i], p.L0[j * 16 + i], a0);
            a1 = fmaf(p.L1[k * 16 + i], p.L1[j * 16 + i], a1);
        }
        if (k == j) { a0 -= expf(p.ll0[0]); a1 -= expf(p.ll1[0]); }
        ws[OFF_M0 + e] = a0;
        ws[OFF_M1 + e] = a1;
    }
}

// Both convs on MFMA — round-0 verified structure (1024 blocks, 8-way
// channel split, 4 blocks/CU). Round-8: when `multi` is set, each channel
// split writes its PARTIAL to its own slice (plain stores, single writer
// per cell) and k2 sums the 8 slices — zero atomics at full occupancy.
// Fallback (multi=0): original atomicAdd combine into slice 0.
__global__ __launch_bounds__(256, 4) void k1_mfma(
    const float* __restrict__ x, const unsigned short* __restrict__ w1a,
    const unsigned short* __restrict__ w2b, float* __restrict__ s2raw,
    int multi) {
    __shared__ float xs[17 * XROW];
    __shared__ unsigned int vsI[2048];      // 4 waves x 8 rows x 64 words

    const int tid = threadIdx.x;
    const int split = blockIdx.x & 7;
    const int tile = (blockIdx.x >> 3) & 7;
    const int b = blockIdx.x >> 6;
    const int c0 = (split * C_) >> 3;
    const int c1 = ((split + 1) * C_) >> 3;
    const int cc = c1 - c0;
    const int t0 = tile << 8;
    const int w = tid >> 6;
    const int lane = tid & 63;
    const int n = lane & 15;
    const int q = lane >> 4;
    const int qh = q >> 1;
    const int q1_2 = (q & 1) * 2;
    const bool q3 = (q == 3);
    const int wb = w << 9;
    const int w64 = w << 6;
    const int ln8 = n + q * 8;

    for (int i = tid; i < 2048; i += 256) vsI[i] = 0u;
    for (int e = tid; e < cc * XROW; e += 256) {
        const int cl = e / XROW;
        const int i = e - cl * XROW;
        const int t = t0 - 12 + i;
        float v = 0.f;
        if ((unsigned)t < (unsigned)T_) v = x[(b * C_ + c0 + cl) * T_ + t];
        xs[e] = v;
    }
    __syncthreads();

    const s8v* w1a8 = (const s8v*)w1a;
    s8v wA[3];
#pragma unroll
    for (int mt = 0; mt < 3; ++mt) wA[mt] = w1a8[mt * 64 + lane];

    f4v acc[4][3];
#pragma unroll
    for (int nt = 0; nt < 4; ++nt)
#pragma unroll
        for (int mt = 0; mt < 3; ++mt) acc[nt][mt] = (f4v)0.f;

    const s8v* w2b8 = (const s8v*)w2b;
    const f4v z4 = (f4v)0.f;

    for (int cl = 0; cl < cc; ++cl) {
        const int c = c0 + cl;
        s8v af[3][2];
#pragma unroll
        for (int mt = 0; mt < 3; ++mt)
#pragma unroll
            for (int kc = 0; kc < 2; ++kc)
                af[mt][kc] = w2b8[((c * 3 + mt) * 2 + kc) * 64 + lane];

        const float* xrow = &xs[cl * XROW + w64 + ln8];

#pragma unroll
        for (int nt = 0; nt < 4; ++nt) {
            float bx[8];
#pragma unroll
            for (int j = 0; j < 8; ++j) bx[j] = xrow[nt * 16 + j];
            if (q3) bx[1] = 1.0f;
            unsigned pw_[4];
#pragma unroll
            for (int jj = 0; jj < 4; ++jj)
                pw_[jj] = bfr(bx[2 * jj]) |
                    ((__float_as_uint(bx[2 * jj + 1]) + 0x8000u) & 0xFFFF0000u);
            const s8v bh = *(const s8v*)pw_;
#pragma unroll
            for (int mt = 0; mt < 3; ++mt) {
                const f4v vT = __builtin_amdgcn_mfma_f32_16x16x32_bf16(
                    wA[mt], bh, z4, 0, 0, 0);
                const float e0 = elu_f(vT[0]);
                const float e1 = elu_f(vT[1]);
                const float e2 = elu_f(vT[2]);
                const float e3 = elu_f(vT[3]);
                const unsigned lo = bfr(e0) |
                    ((__float_as_uint(e1) + 0x8000u) & 0xFFFF0000u);
                const unsigned hi = bfr(e2) |
                    ((__float_as_uint(e3) + 0x8000u) & 0xFFFF0000u);
                const int base = wb + ((2 * mt + qh) << 6) + (n << 2) + q1_2;
                vsI[base] = lo;
                vsI[base + 1] = hi;
            }
            __builtin_amdgcn_wave_barrier();
            const s8v b0 = *(const s8v*)&vsI[wb + (q << 6) + (n << 2)];
            const s8v b1 = *(const s8v*)&vsI[wb + ((4 + q) << 6) + (n << 2)];
#pragma unroll
            for (int mt = 0; mt < 3; ++mt) {
                acc[nt][mt] = __builtin_amdgcn_mfma_f32_16x16x32_bf16(
                    af[mt][0], b0, acc[nt][mt], 0, 0, 0);
                acc[nt][mt] = __builtin_amdgcn_mfma_f32_16x16x32_bf16(
                    af[mt][1], b1, acc[nt][mt], 0, 0, 0);
            }
            __builtin_amdgcn_wave_barrier();
        }
    }

    if (multi) {
        float* dst = s2raw + (size_t)split * SLICE_;
#pragma unroll
        for (int nt = 0; nt < 4; ++nt) {
            const int t = t0 + w * 64 + nt * 16 + n;
            if (t >= T_) continue;
#pragma unroll
            for (int mt = 0; mt < 3; ++mt) {
#pragma unroll
                for (int r = 0; r < 4; ++r) {
                    const int g = mt * 16 + q * 4 + r;
                    if (g < NF_)
                        dst[(b * NF_ + g) * T_ + t] = acc[nt][mt][r];
                }
            }
        }
    } else {
#pragma unroll
        for (int nt = 0; nt < 4; ++nt) {
            const int t = t0 + w * 64 + nt * 16 + n;
            if (t >= T_) continue;
#pragma unroll
            for (int mt = 0; mt < 3; ++mt) {
#pragma unroll
                for (int r = 0; r < 4; ++r) {
                    const int g = mt * 16 + q * 4 + r;
                    if (g < NF_)
                        atomicAdd(&s2raw[(b * NF_ + g) * T_ + t], acc[nt][mt][r]);
                }
            }
        }
    }
}

// Fused dw/pw/pool/proj. Round-8: in multi mode the st load sums the 8
// channel-split partial slices (coalesced reads, pairwise adds).
__global__ __launch_bounds__(256) void k2_dwpw(
    const float* __restrict__ s2raw, const float* __restrict__ sb2,
    const float* __restrict__ dw_w, const float* __restrict__ dw_b,
    const float* __restrict__ pwc, const float* __restrict__ pb2,
    const float* __restrict__ WP, const float* __restrict__ bp,
    float* __restrict__ xp, int multi) {
    __shared__ float st[NF_ * 114];
    __shared__ float dwo[NF_ * 100];
    __shared__ float dwwl[NF_ * 15];
    __shared__ float dwbl[NF_];
    __shared__ float pwcl[80 * 40];
    __shared__ float pb2l[80];
    __shared__ float WPl[K_ * 80];
    __shared__ float bpl[K_];
    __shared__ float po[80 * 25];
    const int tid = threadIdx.x;
    const int b = blockIdx.x / 20;
    const int tp0 = (blockIdx.x % 20) * 25;
    const int tbase = tp0 * 4 - 7;
    for (int e = tid; e < NF_ * 114; e += 256) {
        const int f = e / 114;
        const int i = e - f * 114;
        const int t = tbase + i;
        float v = 0.f;
        if ((unsigned)t < (unsigned)T_) {
            const float* p0 = s2raw + (b * NF_ + f) * T_ + t;
            float s;
            if (multi) {
                const float s01 = p0[0] + p0[SLICE_];
                const float s23 = p0[2 * SLICE_] + p0[3 * SLICE_];
                const float s45 = p0[4 * SLICE_] + p0[5 * SLICE_];
                const float s67 = p0[6 * SLICE_] + p0[7 * SLICE_];
                s = (s01 + s23) + (s45 + s67);
            } else {
                s = p0[0];
            }
            v = elu_f(s + sb2[f]);
        }
        st[e] = v;
    }
    for (int e = tid; e < 600; e += 256) dwwl[e] = dw_w[e];
    for (int e = tid; e < 3200; e += 256) pwcl[e] = pwc[e];
    for (int e = tid; e < 1280; e += 256) WPl[e] = WP[e];
    if (tid < NF_) dwbl[tid] = dw_b[tid];
    if (tid < 80) pb2l[tid] = pb2[tid];
    if (tid < K_) bpl[tid] = bp[tid];
    __syncthreads();
    for (int e = tid; e < 4000; e += 256) {
        const int f = e / 100;
        const int tq = e - f * 100;
        float a = dwbl[f];
#pragma unroll
        for (int kk = 0; kk < 15; ++kk)
            a = fmaf(dwwl[f * 15 + kk], st[f * 114 + tq + kk], a);
        dwo[e] = a;
    }
    __syncthreads();
    for (int e = tid; e < 2000; e += 256) {
        const int g = e / 25;
        const int tp = e - g * 25;
        float sum = 0.f;
#pragma unroll
        for (int dt = 0; dt < 4; ++dt) {
            float a = pb2l[g];
            for (int f = 0; f < NF_; ++f)
                a = fmaf(pwcl[g * 40 + f], dwo[f * 100 + tp * 4 + dt], a);
            sum += elu_f(a);
        }
        po[e] = sum * 0.25f;
    }
    __syncthreads();
    for (int e = tid; e < 400; e += 256) {
        const int tp = e >> 4;
        const int k = e & 15;
        float a = bpl[k];
        for (int g = 0; g < 80; ++g)
            a = fmaf(WPl[k * 80 + g], po[g * 25 + tp], a);
        xp[(b * TP_ + tp0 + tp) * K_ + k] = a;
    }
}

// Scan via readlane broadcast (verified local optimum — frozen).
#define SCAN_STEP(I, S) do {                                              \
    float sH0[16], sH1[16];                                               \
    _Pragma("unroll")                                                     \
    for (int j = 0; j < 16; ++j) {                                        \
        sH0[j] = RDLANE(vA, 32 + j);                                      \
        sH1[j] = RDLANE(vA, j);                                           \
    }                                                                     \
    float a0 = 0.f, a1 = 0.f, a2 = 0.f, a3 = 0.f;                         \
    float c0 = 0.f, c1 = 0.f, c2 = 0.f, c3 = 0.f;                         \
    _Pragma("unroll")                                                     \
    for (int j = 0; j < 16; j += 4) {                                     \
        a0 = fmaf(WA[j],     sH0[j],     a0);                             \
        a1 = fmaf(WA[j + 1], sH0[j + 1], a1);                             \
        a2 = fmaf(WA[j + 2], sH0[j + 2], a2);                             \
        a3 = fmaf(WA[j + 3], sH0[j + 3], a3);                             \
        c0 = fmaf(WB[j],     sH1[j],     c0);                             \
        c1 = fmaf(WB[j + 1], sH1[j + 1], c1);                             \
        c2 = fmaf(WB[j + 2], sH1[j + 2], c2);                             \
        c3 = fmaf(WB[j + 3], sH1[j + 3], c3);                             \
    }                                                                     \
    const float xv = xn[S];                                               \
    int tf = (I) + 5; if (tf > TP_ - 1) tf = TP_ - 1;                     \
    xn[S] = xpb[tf * K_];                                                 \
    const float cadd = lower ? b1r : xv;                                  \
    const float pre = (((a0 + a1) + (a2 + a3)) +                          \
                       ((c0 + c1) + (c2 + c3))) + cadd;                   \
    float s1 = pre, s2 = pre * pre;                                       \
    RSUM16(s1);                                                           \
    RSUM16(s2);                                                           \
    const float mu = s1 * 0.0625f;                                        \
    const float var = fmaf(s2, 0.0625f, -mu * mu);                        \
    vA = tanh2e_f(fmaf((pre - mu) * rsqrtf(var + 1e-5f), gg, bb));        \
} while (0)

__global__ __launch_bounds__(64, 1) void k3_scan(
    const float* __restrict__ xp, const float* __restrict__ M0,
    const float* __restrict__ M1, const float* __restrict__ wx1,
    const float* __restrict__ b1, const float* __restrict__ ln0_g,
    const float* __restrict__ ln0_b, const float* __restrict__ ln1_g,
    const float* __restrict__ ln1_b, float* __restrict__ out) {
    const int lane = threadIdx.x;
    const int k = lane & 15;
    const bool lower = lane < 32;
    const int b = blockIdx.x;

    float WA[16], WB[16];
#pragma unroll
    for (int j = 0; j < 16; ++j) {
        const float m0 = M0[k * 16 + j];
        const float m1 = M1[k * 16 + j];
        const float wx = wx1[k * 16 + j];
        WA[j] = lower ? wx : m0;   // coefficient on h0
        WB[j] = lower ? m1 : 0.f;  // coefficient on h1
    }
    const float b1r = b1[k];
    const float g0 = C2F * ln0_g[k], be0 = C2F * ln0_b[k];
    const float gg = lower ? C2F * ln1_g[k] : g0;
    const float bb = lower ? C2F * ln1_b[k] : be0;
    const float* xpb = xp + b * TP_ * K_ + k;

    // prologue: h0_0 = tanh(LN(x_0)) computed by all lanes
    float h0_0;
    {
        const float x0 = xpb[0];
        float s1 = x0, s2 = x0 * x0;
        RSUM16(s1);
        RSUM16(s2);
        const float mu = s1 * 0.0625f;
        const float var = fmaf(s2, 0.0625f, -mu * mu);
        h0_0 = tanh2e_f(fmaf((x0 - mu) * rsqrtf(var + 1e-5f), g0, be0));
    }
    // vA: upper = h0 state (h0_0), lower = h1 state (h1_{-1} = 0)
    float vA = lower ? 0.f : h0_0;

    float xn[4];
    xn[0] = xpb[1 * K_];
    xn[1] = xpb[2 * K_];
    xn[2] = xpb[3 * K_];
    xn[3] = xpb[4 * K_];

    // iter i (0..499): upper -> h0_{i+1}; lower -> h1_i (uses h0_i, h1_{i-1})
    for (int i = 0; i < TP_; i += 4) {
        SCAN_STEP(i + 0, 0);
        SCAN_STEP(i + 1, 1);
        SCAN_STEP(i + 2, 2);
        SCAN_STEP(i + 3, 3);
    }
    if (lane < 16) {
        out[b * K_ + k] = vA;               // Z = h1_{499} (row 0 state)
        if (k == 0) out[256 + b] = 1.0f;    // alpha = softmax over size-1 axis
    }
}

extern "C" void kernel_launch(void* const* d_in, const int* in_sizes, int n_in,
                              void* d_out, int out_size, void* d_ws, size_t ws_size,
                              hipStream_t stream) {
    const float* x       = (const float*)d_in[0];
    const float* dw_w    = (const float*)d_in[13];
    const float* dw_b    = (const float*)d_in[14];
    const float* wx1     = (const float*)d_in[29];
    const float* b1      = (const float*)d_in[32];
    const float* ln0_g   = (const float*)d_in[27];
    const float* ln0_b   = (const float*)d_in[28];
    const float* ln1_g   = (const float*)d_in[33];
    const float* ln1_b   = (const float*)d_in[34];
    float* ws = (float*)d_ws;
    float* out = (float*)d_out;

    P0 p;
    p.tconv_w = (const float*)d_in[1]; p.tconv_b = (const float*)d_in[2];
    p.tbn_g = (const float*)d_in[3]; p.tbn_b = (const float*)d_in[4];
    p.tbn_m = (const float*)d_in[5]; p.tbn_v = (const float*)d_in[6];
    p.sconv_b = (const float*)d_in[8];
    p.sbn_g = (const float*)d_in[9]; p.sbn_b = (const float*)d_in[10];
    p.sbn_m = (const float*)d_in[11]; p.sbn_v = (const float*)d_in[12];
    p.pw_w = (const float*)d_in[15]; p.pw_b = (const float*)d_in[16];
    p.pbn_g = (const float*)d_in[17]; p.pbn_b = (const float*)d_in[18];
    p.pbn_m = (const float*)d_in[19]; p.pbn_v = (const float*)d_in[20];
    p.proj_w = (const float*)d_in[21]; p.proj_b = (const float*)d_in[22];
    p.wx0 = (const float*)d_in[23]; p.b0 = (const float*)d_in[26];
    p.L0 = (const float*)d_in[24]; p.ll0 = (const float*)d_in[25];
    p.L1 = (const float*)d_in[30]; p.ll1 = (const float*)d_in[31];
    p.sconv_w = (const float*)d_in[7];
    p.ws = ws;

    unsigned short* w2b = (unsigned short*)(ws + OFF_W2U);
    unsigned short* w1a = (unsigned short*)(ws + OFF_W1A);

    // sliced (atomic-free) combine needs 8 partial slices in the workspace
    const int multi =
        (ws_size >= (size_t)(OFF_S2R + 8 * SLICE_) * sizeof(float)) ? 1 : 0;

    k0_all<<<dim3(1452), dim3(256), 0, stream>>>(p);
    k1_mfma<<<dim3(1024), dim3(256), 0, stream>>>(x, w1a, w2b, ws + OFF_S2R,
                                                  multi);
    k2_dwpw<<<dim3(320), dim3(256), 0, stream>>>(ws + OFF_S2R, ws + OFF_SB2,
                                                 dw_w, dw_b, ws + OFF_PWC,
                                                 ws + OFF_PB2, ws + OFF_WP, ws + OFF_BP,
                                                 ws + OFF_XP, multi);
    k3_scan<<<dim3(16), dim3(64), 0, stream>>>(ws + OFF_XP, ws + OFF_M0, ws + OFF_M1,
                                               wx1, b1, ln0_g, ln0_b, ln1_g, ln1_b, out);
}